// Round 1
// baseline (395.806 us; speedup 1.0000x reference)
//
#include <hip/hip_runtime.h>

// ---------------------------------------------------------------------------
// localTransformer: the attention is dead code (softmax over a singleton axis
// == 1, so o == v). Each depth iter is x <- MLP_g(Wv@x + bv) per pixel, and
// the MLP entry/exit linears fold into the adjacent 1x1 convs. Whole net:
//   OUT = Wd0@X0 + Wd2p@gelu(A12@gelu(A1@X0 + b1p) + b12p) + bdp
// with A1/A12/Wd2p dense 256x256, precomputed per call in d_ws (bf16, packed
// in MFMA A-fragment order). One fused kernel does everything per pixel tile.
// ---------------------------------------------------------------------------

typedef short v8s __attribute__((ext_vector_type(8)));   // 8 bf16 (4 VGPRs)
typedef float v4f __attribute__((ext_vector_type(4)));   // MFMA C/D

#define L_   16384        // H*W
#define PIX  64           // pixels per block
#define XROW 264          // LDS row stride in bf16 (256 + 8 pad: 16B-aligned,
                          // p-stride 528B -> 2-way bank conflicts only)

__device__ __forceinline__ unsigned short bf16rne(float f) {
  union { float f; unsigned u; } v; v.f = f;
  unsigned u = v.u;
  return (unsigned short)((u + 0x7FFFu + ((u >> 16) & 1u)) >> 16);
}

__device__ __forceinline__ float gelu_exact(float x) {
  return 0.5f * x * (1.0f + erff(x * 0.70710678118654752f));
}

// ---------------- prep kernels: fold + bf16-pack weights ----------------
// pack order: idx = ((mt*8 + kt)*64 + lane)*8 + j
//   -> element A[mt*16 + (lane&15)][kt*32 + (lane>>4)*8 + j]

__global__ void pack_wd0_k(const float* __restrict__ Wd, unsigned short* __restrict__ dst) {
  int tid = blockIdx.x * 256 + threadIdx.x;
  int j = tid & 7, lane = (tid >> 3) & 63, kt = (tid >> 9) & 7, mt = tid >> 12;
  int m = mt * 16 + (lane & 15);
  int k = kt * 32 + (lane >> 4) * 8 + j;
  dst[tid] = bf16rne(Wd[m * 512 + k]);                 // Wd0 = Wd[:, :256]
}

__global__ void pack_a1_k(const float* __restrict__ Wv, const float* __restrict__ W1,
                          unsigned short* __restrict__ dst) {
  int tid = blockIdx.x * 256 + threadIdx.x;
  int j = tid & 7, lane = (tid >> 3) & 63, kt = (tid >> 9) & 7, mt = tid >> 12;
  int m = mt * 16 + (lane & 15);                       // h1 = jp*16 + c
  int k = kt * 32 + (lane >> 4) * 8 + j;               // input channel
  int jp = m >> 4, c = m & 15;
  float s = 0.f;
  for (int g = 0; g < 16; ++g) s += W1[g * 16 + jp] * Wv[(g * 16 + c) * 256 + k];
  dst[tid] = bf16rne(s);
}

__global__ void pack_a12_k(const float* __restrict__ Wv, const float* __restrict__ W1,
                           const float* __restrict__ W2, unsigned short* __restrict__ dst) {
  int tid = blockIdx.x * 256 + threadIdx.x;
  int j = tid & 7, lane = (tid >> 3) & 63, kt = (tid >> 9) & 7, mt = tid >> 12;
  int m = mt * 16 + (lane & 15);                       // h2 = jp*16 + cp
  int k = kt * 32 + (lane >> 4) * 8 + j;               // h1 = jj*16 + c
  int jp = m >> 4, cp = m & 15;
  int jj = k >> 4, c = k & 15;
  float s = 0.f;
  for (int g = 0; g < 16; ++g) {
    float inner = 0.f;
    for (int j2 = 0; j2 < 16; ++j2)
      inner += Wv[(g * 16 + cp) * 256 + j2 * 16 + c] * W2[jj * 16 + j2];
    s += W1[g * 16 + jp] * inner;
  }
  dst[tid] = bf16rne(s);
}

__global__ void pack_wd2_k(const float* __restrict__ Wd, const float* __restrict__ W2,
                           unsigned short* __restrict__ dst) {
  int tid = blockIdx.x * 256 + threadIdx.x;
  int j = tid & 7, lane = (tid >> 3) & 63, kt = (tid >> 9) & 7, mt = tid >> 12;
  int o = mt * 16 + (lane & 15);
  int k = kt * 32 + (lane >> 4) * 8 + j;               // h2 = jj*16 + c
  int jj = k >> 4, c = k & 15;
  float s = 0.f;
  for (int j2 = 0; j2 < 16; ++j2)
    s += Wd[o * 512 + 256 + j2 * 16 + c] * W2[jj * 16 + j2];
  dst[tid] = bf16rne(s);
}

__global__ void bias1_k(const float* __restrict__ Wv, const float* __restrict__ bv,
                        const float* __restrict__ Wd, const float* __restrict__ b2,
                        const float* __restrict__ bd,
                        float* __restrict__ tmpT, float* __restrict__ bdp) {
  int h = threadIdx.x;                                 // 256 threads
  int g = h >> 4, cp = h & 15;
  // tmpT[g][cp] = bv[g*16+cp] + sum_{j2,c} Wv[g*16+cp][j2*16+c] * b2[j2]
  float s = bv[g * 16 + cp];
  for (int j2 = 0; j2 < 16; ++j2) {
    float b2v = b2[j2];
    for (int c = 0; c < 16; ++c) s += Wv[(g * 16 + cp) * 256 + j2 * 16 + c] * b2v;
  }
  tmpT[h] = s;
  // bdp[o] = bd[o] + sum_{j2,c} Wd[o][256 + j2*16 + c] * b2[j2]
  float sd = bd[h];
  for (int j2 = 0; j2 < 16; ++j2) {
    float b2v = b2[j2];
    for (int c = 0; c < 16; ++c) sd += Wd[h * 512 + 256 + j2 * 16 + c] * b2v;
  }
  bdp[h] = sd;
}

__global__ void bias2_k(const float* __restrict__ W1, const float* __restrict__ b1,
                        const float* __restrict__ bv, const float* __restrict__ tmpT,
                        float* __restrict__ b1p, float* __restrict__ b12p) {
  int h = threadIdx.x;                                 // 256 threads
  int j = h >> 4, c = h & 15;
  float s1 = b1[j], s2 = b1[j];
  for (int g = 0; g < 16; ++g) {
    float w = W1[g * 16 + j];
    s1 += w * bv[g * 16 + c];
    s2 += w * tmpT[g * 16 + c];
  }
  b1p[h] = s1;
  b12p[h] = s2;
}

// ---------------- fused main kernel ----------------

__device__ __forceinline__ void gemm_pass(const unsigned short* __restrict__ packA,
                                          const short* __restrict__ XB,
                                          int w, int lane, v4f acc[4][4]) {
  int l15 = lane & 15, quad = lane >> 4;
#pragma unroll
  for (int kt = 0; kt < 8; ++kt) {
    v8s bf[4];
#pragma unroll
    for (int nt = 0; nt < 4; ++nt)
      bf[nt] = *(const v8s*)&XB[(nt * 16 + l15) * XROW + kt * 32 + quad * 8];
#pragma unroll
    for (int mi = 0; mi < 4; ++mi) {
      int fo = (((w * 4 + mi) * 8 + kt) * 64 + lane) * 8;
      v8s a = *(const v8s*)(packA + fo);
#pragma unroll
      for (int nt = 0; nt < 4; ++nt)
        acc[mi][nt] = __builtin_amdgcn_mfma_f32_16x16x32_bf16(a, bf[nt], acc[mi][nt], 0, 0, 0);
    }
  }
}

__device__ __forceinline__ void epi_gelu_store(v4f acc[4][4], const float* __restrict__ bias,
                                               short* __restrict__ XB, int w, int lane) {
  int l15 = lane & 15, quad = lane >> 4;
#pragma unroll
  for (int mi = 0; mi < 4; ++mi) {
    int rb = (w * 4 + mi) * 16 + quad * 4;             // row base (4 consecutive rows)
    float b0 = bias[rb], b1v = bias[rb + 1], b2v = bias[rb + 2], b3v = bias[rb + 3];
#pragma unroll
    for (int nt = 0; nt < 4; ++nt) {
      int p = nt * 16 + l15;
      float g0 = gelu_exact(acc[mi][nt][0] + b0);
      float g1 = gelu_exact(acc[mi][nt][1] + b1v);
      float g2 = gelu_exact(acc[mi][nt][2] + b2v);
      float g3 = gelu_exact(acc[mi][nt][3] + b3v);
      unsigned u01 = (unsigned)bf16rne(g0) | ((unsigned)bf16rne(g1) << 16);
      unsigned u23 = (unsigned)bf16rne(g2) | ((unsigned)bf16rne(g3) << 16);
      *(unsigned*)&XB[p * XROW + rb]     = u01;
      *(unsigned*)&XB[p * XROW + rb + 2] = u23;
      acc[mi][nt] = (v4f){0.f, 0.f, 0.f, 0.f};
    }
  }
}

__global__ __launch_bounds__(256, 2) void fused_k(
    const float* __restrict__ x,
    const unsigned short* __restrict__ pWd0, const unsigned short* __restrict__ pA1,
    const unsigned short* __restrict__ pA12, const unsigned short* __restrict__ pWd2,
    const float* __restrict__ b1p, const float* __restrict__ b12p,
    const float* __restrict__ bdp, float* __restrict__ out) {
  __shared__ __align__(16) short XB[PIX * XROW];
  int t = threadIdx.x;
  int lane = t & 63, w = t >> 6;
  int quad = lane >> 4, l15 = lane & 15;
  long pp0 = (long)blockIdx.x * PIX;
  int b = (int)(pp0 >> 14);
  int l0 = (int)(pp0 & 16383);
  const float* xb = x + ((long)b << 22) + l0;

  // Phase 1: stage X0 tile -> bf16, transposed [pixel][channel] in LDS.
  // lane: sub = p within wave's 16, cp selects channel pair; banks 2-way only.
  {
    int sub = lane >> 2, cp = lane & 3;
    int p = (w << 4) | sub;
#pragma unroll
    for (int i = 0; i < 32; ++i) {
      int ch0 = (i << 3) | (cp << 1);
      float f0 = xb[(long)ch0 * L_ + p];
      float f1 = xb[(long)(ch0 + 1) * L_ + p];
      unsigned u = (unsigned)bf16rne(f0) | ((unsigned)bf16rne(f1) << 16);
      *(unsigned*)&XB[p * XROW + ch0] = u;
    }
  }

  v4f outacc[4][4], hacc[4][4];
#pragma unroll
  for (int i = 0; i < 4; ++i)
#pragma unroll
    for (int j = 0; j < 4; ++j) {
      outacc[i][j] = (v4f){0.f, 0.f, 0.f, 0.f};
      hacc[i][j]   = (v4f){0.f, 0.f, 0.f, 0.f};
    }

  __syncthreads();

  // Phase 2: dual GEMM on X0 (shared B-frags): OUT += Wd0@X0, H1 = A1@X0
#pragma unroll
  for (int kt = 0; kt < 8; ++kt) {
    v8s bf[4];
#pragma unroll
    for (int nt = 0; nt < 4; ++nt)
      bf[nt] = *(const v8s*)&XB[(nt * 16 + l15) * XROW + kt * 32 + quad * 8];
#pragma unroll
    for (int mi = 0; mi < 4; ++mi) {
      int fo = (((w * 4 + mi) * 8 + kt) * 64 + lane) * 8;
      v8s a1 = *(const v8s*)(pA1 + fo);
      v8s a0 = *(const v8s*)(pWd0 + fo);
#pragma unroll
      for (int nt = 0; nt < 4; ++nt) {
        hacc[mi][nt]   = __builtin_amdgcn_mfma_f32_16x16x32_bf16(a1, bf[nt], hacc[mi][nt], 0, 0, 0);
        outacc[mi][nt] = __builtin_amdgcn_mfma_f32_16x16x32_bf16(a0, bf[nt], outacc[mi][nt], 0, 0, 0);
      }
    }
  }

  __syncthreads();
  epi_gelu_store(hacc, b1p, XB, w, lane);   // H1 = gelu(. + b1p) -> LDS (bf16)
  __syncthreads();
  gemm_pass(pA12, XB, w, lane, hacc);       // H2pre = A12 @ H1
  __syncthreads();
  epi_gelu_store(hacc, b12p, XB, w, lane);  // H2 = gelu(. + b12p) -> LDS
  __syncthreads();
  gemm_pass(pWd2, XB, w, lane, outacc);     // OUT += Wd2p @ H2

  // Phase 7: OUT + bdp -> global (fp32), 64B segments per quad
  long obase = ((long)b << 22) + l0;
#pragma unroll
  for (int mi = 0; mi < 4; ++mi) {
    int rb = (w * 4 + mi) * 16 + quad * 4;
    float bb0 = bdp[rb], bb1 = bdp[rb + 1], bb2 = bdp[rb + 2], bb3 = bdp[rb + 3];
#pragma unroll
    for (int nt = 0; nt < 4; ++nt) {
      int p = nt * 16 + l15;
      out[obase + (long)(rb + 0) * L_ + p] = outacc[mi][nt][0] + bb0;
      out[obase + (long)(rb + 1) * L_ + p] = outacc[mi][nt][1] + bb1;
      out[obase + (long)(rb + 2) * L_ + p] = outacc[mi][nt][2] + bb2;
      out[obase + (long)(rb + 3) * L_ + p] = outacc[mi][nt][3] + bb3;
    }
  }
}

// ---------------- launch ----------------

extern "C" void kernel_launch(void* const* d_in, const int* in_sizes, int n_in,
                              void* d_out, int out_size, void* d_ws, size_t ws_size,
                              hipStream_t stream) {
  const float* x  = (const float*)d_in[0];
  const float* Wv = (const float*)d_in[3];
  const float* bv = (const float*)d_in[4];
  const float* W1 = (const float*)d_in[13];
  const float* b1 = (const float*)d_in[14];
  const float* W2 = (const float*)d_in[15];
  const float* b2 = (const float*)d_in[16];
  const float* Wd = (const float*)d_in[17];
  const float* bd = (const float*)d_in[18];
  float* out = (float*)d_out;

  char* ws = (char*)d_ws;
  unsigned short* pWd0 = (unsigned short*)(ws + 0);
  unsigned short* pA1  = (unsigned short*)(ws + 131072);
  unsigned short* pA12 = (unsigned short*)(ws + 262144);
  unsigned short* pWd2 = (unsigned short*)(ws + 393216);
  float* b1p  = (float*)(ws + 524288);
  float* b12p = (float*)(ws + 525312);
  float* bdp  = (float*)(ws + 526336);
  float* tmpT = (float*)(ws + 527360);

  pack_wd0_k<<<256, 256, 0, stream>>>(Wd, pWd0);
  pack_a1_k <<<256, 256, 0, stream>>>(Wv, W1, pA1);
  pack_a12_k<<<256, 256, 0, stream>>>(Wv, W1, W2, pA12);
  pack_wd2_k<<<256, 256, 0, stream>>>(Wd, W2, pWd2);
  bias1_k<<<1, 256, 0, stream>>>(Wv, bv, Wd, b2, bd, tmpT, bdp);
  bias2_k<<<1, 256, 0, stream>>>(W1, b1, bv, tmpT, b1p, b12p);

  fused_k<<<2048, 256, 0, stream>>>(x, pWd0, pA1, pA12, pWd2, b1p, b12p, bdp, out);
}